// Round 4
// baseline (95511.713 us; speedup 1.0000x reference)
//
#include <hip/hip_runtime.h>
#include <hip/hip_cooperative_groups.h>
#include <math.h>

namespace cg = cooperative_groups;

#define BB 128
#define NN 256
#define NP1 257
#define HH 1024
#define H4 4096

// pad-4-every-32 column map for k-major LDS tiles: 2-way bank conflicts only
#define CPHI(m) ((m) + (((m) >> 5) << 2))

// ---------------------------------------------------------------------------
// encWa[r, n] = sum_k ext[r,k] * Wa[n,k];  grid (257, 8), 256 thr, 128x128 tile
__global__ __launch_bounds__(256, 2) void k_encWa2(const float* __restrict__ enc,
                                                   const float* __restrict__ etok,
                                                   const float* __restrict__ Wa,
                                                   float* __restrict__ out) {
    __shared__ float As[32][140];
    __shared__ float Ws[32][140];
    const int mt = blockIdx.x, ntl = blockIdx.y;
    const int tid = threadIdx.x;
    const int lr = tid >> 2, lc = tid & 3;
    const int tr = tid & 15, tc = tid >> 4;

    const int r0 = mt * 128 + lr, r1 = r0 + 64;
    const int bb0 = r0 / NP1, nn0 = r0 - bb0 * NP1;
    const int bb1 = r1 / NP1, nn1 = r1 - bb1 * NP1;
    const float* a0 = (nn0 == NN) ? etok : enc + ((size_t)(bb0 * NN + nn0)) * HH;
    const float* a1 = (nn1 == NN) ? etok : enc + ((size_t)(bb1 * NN + nn1)) * HH;
    const float* w0 = Wa + (size_t)(ntl * 128 + lr) * HH;
    const float* w1 = w0 + (size_t)64 * HH;
    const int ca = CPHI(lr), cb = CPHI(lr + 64);
    const int colA = tr * 8 + ((tr >> 2) << 2);
    const int colB = tc * 8 + ((tc >> 2) << 2);

    float acc[8][8] = {};
    for (int k0 = 0; k0 < HH; k0 += 32) {
        float4 va0 = *(const float4*)(a0 + k0 + lc * 4);
        float4 va1 = *(const float4*)(a0 + k0 + lc * 4 + 16);
        float4 va2 = *(const float4*)(a1 + k0 + lc * 4);
        float4 va3 = *(const float4*)(a1 + k0 + lc * 4 + 16);
        float4 vb0 = *(const float4*)(w0 + k0 + lc * 4);
        float4 vb1 = *(const float4*)(w0 + k0 + lc * 4 + 16);
        float4 vb2 = *(const float4*)(w1 + k0 + lc * 4);
        float4 vb3 = *(const float4*)(w1 + k0 + lc * 4 + 16);
        __syncthreads();
        #pragma unroll
        for (int e = 0; e < 4; e++) {
            As[lc*4+e][ca]      = ((const float*)&va0)[e];
            As[lc*4+16+e][ca]   = ((const float*)&va1)[e];
            As[lc*4+e][cb]      = ((const float*)&va2)[e];
            As[lc*4+16+e][cb]   = ((const float*)&va3)[e];
            Ws[lc*4+e][ca]      = ((const float*)&vb0)[e];
            Ws[lc*4+16+e][ca]   = ((const float*)&vb1)[e];
            Ws[lc*4+e][cb]      = ((const float*)&vb2)[e];
            Ws[lc*4+16+e][cb]   = ((const float*)&vb3)[e];
        }
        __syncthreads();
        #pragma unroll
        for (int kk = 0; kk < 32; kk++) {
            float4 A0 = *(const float4*)&As[kk][colA];
            float4 A1 = *(const float4*)&As[kk][colA + 4];
            float4 B0 = *(const float4*)&Ws[kk][colB];
            float4 B1 = *(const float4*)&Ws[kk][colB + 4];
            float av[8] = {A0.x,A0.y,A0.z,A0.w,A1.x,A1.y,A1.z,A1.w};
            float bv[8] = {B0.x,B0.y,B0.z,B0.w,B1.x,B1.y,B1.z,B1.w};
            #pragma unroll
            for (int i = 0; i < 8; i++)
                #pragma unroll
                for (int j = 0; j < 8; j++) acc[i][j] += av[i] * bv[j];
        }
        __syncthreads();
    }
    #pragma unroll
    for (int i = 0; i < 8; i++) {
        float4 o0 = make_float4(acc[i][0], acc[i][1], acc[i][2], acc[i][3]);
        float4 o1 = make_float4(acc[i][4], acc[i][5], acc[i][6], acc[i][7]);
        float* dst = out + (size_t)(mt * 128 + tr * 8 + i) * HH + ntl * 128 + tc * 8;
        *(float4*)(dst) = o0;
        *(float4*)(dst + 4) = o1;
    }
}

// ---------------------------------------------------------------------------
// Cooperative mega-kernel: the whole 257-step decode loop.
// 512 blocks x 256 threads, 2 blocks/CU. 5 grid.sync() per step.
// Phase bodies are identical math to the round-3 kernels (same summation
// order -> same argmax decisions).
__global__ __launch_bounds__(256, 2) void k_decode(const float* __restrict__ enc,
                                                   const float* __restrict__ stok,
                                                   const float* __restrict__ etok,
                                                   const float* __restrict__ Wih,
                                                   const float* __restrict__ Whh,
                                                   const float* __restrict__ bih,
                                                   const float* __restrict__ bhh,
                                                   const float* __restrict__ Ua,
                                                   const float* __restrict__ vvec,
                                                   const float* __restrict__ encWa,
                                                   float* __restrict__ gp,
                                                   float* __restrict__ hup,
                                                   float* __restrict__ hx,
                                                   float* __restrict__ cx,
                                                   float* __restrict__ scores,
                                                   int* __restrict__ mask,
                                                   int* __restrict__ cur,
                                                   float* __restrict__ out_lp,
                                                   float* __restrict__ out_idx) {
    cg::grid_group grid = cg::this_grid();
    const int bid = blockIdx.x;
    const int t = threadIdx.x;
    __shared__ __align__(16) float smem[2 * 32 * 140];   // 35.84 KB arena
    float* Asm = smem;
    float* Wsm = smem + 32 * 140;

    // ---- init (replaces k_init) ----
    {
        int i = bid * 256 + t;
        if (i < BB * HH) { hx[i] = 0.f; cx[i] = 0.f; }
        if (i < BB * NP1) mask[i] = 0;
        if (i < BB) cur[i] = -1;
    }
    grid.sync();

    for (int step = 0; step < NP1; step++) {
        // ================= phase A: gates partials (all 512 blocks) ========
        {
            const int nt = bid & 31, ks = bid >> 5;     // 32 n-tiles, 16 k-splits
            const int lr = t >> 2, lc = t & 3;
            const int tr = t & 15, tc = t >> 4;
            const int kbase = ks * 128;
            const bool xpart = (kbase < HH);
            const float *arow0, *arow1;
            if (xpart) {
                int c0 = cur[lr], c1 = cur[lr + 64];
                arow0 = (c0 < 0) ? stok : (c0 == NN ? etok : enc + ((size_t)lr * NN + c0) * HH);
                arow1 = (c1 < 0) ? stok : (c1 == NN ? etok : enc + ((size_t)(lr + 64) * NN + c1) * HH);
                arow0 += kbase; arow1 += kbase;
            } else {
                arow0 = hx + (size_t)lr * HH + (kbase - HH);
                arow1 = hx + (size_t)(lr + 64) * HH + (kbase - HH);
            }
            const float* wbp = xpart ? Wih : Whh;
            const int krel = kbase & (HH - 1);
            const float* w0 = wbp + (size_t)(nt * 128 + lr) * HH + krel;
            const float* w1 = w0 + (size_t)64 * HH;
            const int ca = CPHI(lr), cb = CPHI(lr + 64);
            const int colA = tr * 8 + ((tr >> 2) << 2);
            const int colB = tc * 8 + ((tc >> 2) << 2);

            float acc[8][8] = {};
            for (int k0 = 0; k0 < 128; k0 += 32) {
                float4 va0 = *(const float4*)(arow0 + k0 + lc * 4);
                float4 va1 = *(const float4*)(arow0 + k0 + lc * 4 + 16);
                float4 va2 = *(const float4*)(arow1 + k0 + lc * 4);
                float4 va3 = *(const float4*)(arow1 + k0 + lc * 4 + 16);
                float4 vb0 = *(const float4*)(w0 + k0 + lc * 4);
                float4 vb1 = *(const float4*)(w0 + k0 + lc * 4 + 16);
                float4 vb2 = *(const float4*)(w1 + k0 + lc * 4);
                float4 vb3 = *(const float4*)(w1 + k0 + lc * 4 + 16);
                __syncthreads();
                #pragma unroll
                for (int e = 0; e < 4; e++) {
                    Asm[(lc*4+e)*140 + ca]    = ((const float*)&va0)[e];
                    Asm[(lc*4+16+e)*140 + ca] = ((const float*)&va1)[e];
                    Asm[(lc*4+e)*140 + cb]    = ((const float*)&va2)[e];
                    Asm[(lc*4+16+e)*140 + cb] = ((const float*)&va3)[e];
                    Wsm[(lc*4+e)*140 + ca]    = ((const float*)&vb0)[e];
                    Wsm[(lc*4+16+e)*140 + ca] = ((const float*)&vb1)[e];
                    Wsm[(lc*4+e)*140 + cb]    = ((const float*)&vb2)[e];
                    Wsm[(lc*4+16+e)*140 + cb] = ((const float*)&vb3)[e];
                }
                __syncthreads();
                #pragma unroll
                for (int kk = 0; kk < 32; kk++) {
                    float4 A0 = *(const float4*)&Asm[kk*140 + colA];
                    float4 A1 = *(const float4*)&Asm[kk*140 + colA + 4];
                    float4 B0 = *(const float4*)&Wsm[kk*140 + colB];
                    float4 B1 = *(const float4*)&Wsm[kk*140 + colB + 4];
                    float av[8] = {A0.x,A0.y,A0.z,A0.w,A1.x,A1.y,A1.z,A1.w};
                    float bv[8] = {B0.x,B0.y,B0.z,B0.w,B1.x,B1.y,B1.z,B1.w};
                    #pragma unroll
                    for (int i = 0; i < 8; i++)
                        #pragma unroll
                        for (int j = 0; j < 8; j++) acc[i][j] += av[i] * bv[j];
                }
                __syncthreads();
            }
            #pragma unroll
            for (int i = 0; i < 8; i++) {
                float4 o0 = make_float4(acc[i][0], acc[i][1], acc[i][2], acc[i][3]);
                float4 o1 = make_float4(acc[i][4], acc[i][5], acc[i][6], acc[i][7]);
                float* dst = gp + ((size_t)ks * 128 + tr * 8 + i) * H4 + nt * 128 + tc * 8;
                *(float4*)(dst) = o0;
                *(float4*)(dst + 4) = o1;
            }
        }
        grid.sync();

        // ================= phase B: reduce + LSTM cell (blocks 0..127) =====
        if (bid < 128) {
            const int q = bid * 256 + t;
            const int m = q >> 8, c0 = (q & 255) * 4;
            float4 s[4] = {};
            for (int ks = 0; ks < 16; ks++) {
                const float* base = gp + ((size_t)ks * 128 + m) * H4;
                #pragma unroll
                for (int g = 0; g < 4; g++) {
                    float4 vv4 = *(const float4*)(base + g * HH + c0);
                    s[g].x += vv4.x; s[g].y += vv4.y; s[g].z += vv4.z; s[g].w += vv4.w;
                }
            }
            float4 b1[4], b2[4];
            #pragma unroll
            for (int g = 0; g < 4; g++) {
                b1[g] = *(const float4*)(bih + g * HH + c0);
                b2[g] = *(const float4*)(bhh + g * HH + c0);
            }
            float4 cxv = *(const float4*)(cx + (size_t)m * HH + c0);
            float hn[4], cn[4];
            #pragma unroll
            for (int e = 0; e < 4; e++) {
                float gi = ((const float*)&s[0])[e] + ((const float*)&b1[0])[e] + ((const float*)&b2[0])[e];
                float gf = ((const float*)&s[1])[e] + ((const float*)&b1[1])[e] + ((const float*)&b2[1])[e];
                float gg = ((const float*)&s[2])[e] + ((const float*)&b1[2])[e] + ((const float*)&b2[2])[e];
                float go = ((const float*)&s[3])[e] + ((const float*)&b1[3])[e] + ((const float*)&b2[3])[e];
                float si = 1.f / (1.f + expf(-gi));
                float sf = 1.f / (1.f + expf(-gf));
                float so = 1.f / (1.f + expf(-go));
                float c = sf * ((const float*)&cxv)[e] + si * tanhf(gg);
                cn[e] = c;
                hn[e] = so * tanhf(c);
            }
            *(float4*)(cx + (size_t)m * HH + c0) = make_float4(cn[0], cn[1], cn[2], cn[3]);
            *(float4*)(hx + (size_t)m * HH + c0) = make_float4(hn[0], hn[1], hn[2], hn[3]);
        }
        grid.sync();

        // ================= phase C: hUa partials (blocks 0..255) ===========
        if (bid < 256) {
            const int nt = bid & 15, sh = bid >> 4;    // 16 n-tiles, 16 k-splits
            const int lr = t >> 2, lc = t & 3;
            const int tr = t & 15, tc = t >> 4;
            const int kbase = sh * 64;
            const float* a0 = hx + (size_t)lr * HH + kbase;
            const float* a1 = hx + (size_t)(lr + 64) * HH + kbase;
            const float* u0 = Ua + (size_t)(nt * 64 + lr) * HH + kbase;
            const int ca = CPHI(lr), cb = CPHI(lr + 64);
            const int colA = tr * 8 + ((tr >> 2) << 2);
            float* Usm = Wsm;   // stride 72 region inside arena

            float acc[8][4] = {};
            for (int k0 = 0; k0 < 64; k0 += 32) {
                float4 va0 = *(const float4*)(a0 + k0 + lc * 4);
                float4 va1 = *(const float4*)(a0 + k0 + lc * 4 + 16);
                float4 va2 = *(const float4*)(a1 + k0 + lc * 4);
                float4 va3 = *(const float4*)(a1 + k0 + lc * 4 + 16);
                float4 vu0 = *(const float4*)(u0 + k0 + lc * 4);
                float4 vu1 = *(const float4*)(u0 + k0 + lc * 4 + 16);
                __syncthreads();
                #pragma unroll
                for (int e = 0; e < 4; e++) {
                    Asm[(lc*4+e)*140 + ca]    = ((const float*)&va0)[e];
                    Asm[(lc*4+16+e)*140 + ca] = ((const float*)&va1)[e];
                    Asm[(lc*4+e)*140 + cb]    = ((const float*)&va2)[e];
                    Asm[(lc*4+16+e)*140 + cb] = ((const float*)&va3)[e];
                    Usm[(lc*4+e)*72 + lr]     = ((const float*)&vu0)[e];
                    Usm[(lc*4+16+e)*72 + lr]  = ((const float*)&vu1)[e];
                }
                __syncthreads();
                #pragma unroll
                for (int kk = 0; kk < 32; kk++) {
                    float4 A0 = *(const float4*)&Asm[kk*140 + colA];
                    float4 A1 = *(const float4*)&Asm[kk*140 + colA + 4];
                    float4 U0 = *(const float4*)&Usm[kk*72 + tc * 4];
                    float av[8] = {A0.x,A0.y,A0.z,A0.w,A1.x,A1.y,A1.z,A1.w};
                    float uv[4] = {U0.x,U0.y,U0.z,U0.w};
                    #pragma unroll
                    for (int i = 0; i < 8; i++)
                        #pragma unroll
                        for (int j = 0; j < 4; j++) acc[i][j] += av[i] * uv[j];
                }
                __syncthreads();
            }
            #pragma unroll
            for (int i = 0; i < 8; i++) {
                float4 o = make_float4(acc[i][0], acc[i][1], acc[i][2], acc[i][3]);
                *(float4*)(hup + ((size_t)sh * 128 + tr * 8 + i) * HH + nt * 64 + tc * 4) = o;
            }
        }
        grid.sync();

        // ================= phase D: scores (all 512 blocks, 4/batch) =======
        {
            const int b = bid >> 2, q = bid & 3;
            float* hu = smem;          // [1024]
            float* vv = smem + HH;     // [1024]
            {
                float4 s = {};
                for (int sh = 0; sh < 16; sh++) {
                    float4 p = *(const float4*)(hup + ((size_t)sh * 128 + b) * HH + t * 4);
                    s.x += p.x; s.y += p.y; s.z += p.z; s.w += p.w;
                }
                *(float4*)(&hu[t * 4]) = s;
                *(float4*)(&vv[t * 4]) = *(const float4*)(vvec + t * 4);
            }
            __syncthreads();
            const int wave = t >> 6, lane = t & 63;
            const int limit = (q == 3) ? NP1 : (q + 1) * 64;
            int n = q * 64 + wave;
            if (n < limit) {
                const float4 hh4 = *(const float4*)(&hu[lane * 4]);
                const float4 vv4 = *(const float4*)(&vv[lane * 4]);
                float4 e = *(const float4*)(encWa + ((size_t)b * NP1 + n) * HH + lane * 4);
                while (n < limit) {
                    int n2 = n + 4;
                    float4 e2 = e;
                    if (n2 < limit)
                        e2 = *(const float4*)(encWa + ((size_t)b * NP1 + n2) * HH + lane * 4);
                    float s = vv4.x * tanhf(e.x + hh4.x) + vv4.y * tanhf(e.y + hh4.y)
                            + vv4.z * tanhf(e.z + hh4.z) + vv4.w * tanhf(e.w + hh4.w);
                    #pragma unroll
                    for (int off = 32; off; off >>= 1) s += __shfl_down(s, off);
                    if (lane == 0) scores[b * NP1 + n] = s;
                    e = e2; n = n2;
                }
            }
            __syncthreads();
        }
        grid.sync();

        // ================= phase E: finalize (blocks 0..127) ===============
        if (bid < 128) {
            const int b = bid;
            float* rv = smem;                    // [256]
            int*   ri = (int*)(smem + 256);      // [256]
            const bool m_t = mask[b * NP1 + t] != 0;
            const float va = m_t ? -INFINITY : scores[b * NP1 + t];
            float va256 = 0.f;
            if (t == 0) va256 = (mask[b * NP1 + NN] != 0) ? -INFINITY : scores[b * NP1 + NN];

            float myv = va; int myi = t;
            if (t == 0) { if (va256 > myv) { myv = va256; myi = NN; } }
            rv[t] = myv; ri[t] = myi;
            __syncthreads();
            for (int s = 128; s; s >>= 1) {
                if (t < s) {
                    float ov = rv[t + s]; int oi = ri[t + s];
                    if (ov > rv[t] || (ov == rv[t] && oi < ri[t])) { rv[t] = ov; ri[t] = oi; }
                }
                __syncthreads();
            }
            const float vmax = rv[0]; const int amax = ri[0];
            __syncthreads();

            float es = expf(va - vmax);
            if (t == 0) es += expf(va256 - vmax);
            rv[t] = es;
            __syncthreads();
            for (int s = 128; s; s >>= 1) {
                if (t < s) rv[t] += rv[t + s];
                __syncthreads();
            }
            const float lse = vmax + logf(rv[0]);

            out_lp[((size_t)b * NP1 + step) * NP1 + t] = fmaxf(va - lse, -1e30f);
            if (t == 0) {
                out_lp[((size_t)b * NP1 + step) * NP1 + NN] = fmaxf(va256 - lse, -1e30f);
                out_idx[(size_t)b * NP1 + step] = (float)amax;
                cur[b] = amax;
                if (amax < NN) mask[b * NP1 + amax] = 1;
            }
        }
        grid.sync();
    }
}

// ===========================================================================
// ================ fallback path (round-3 separate kernels) =================
__global__ __launch_bounds__(256) void k_init(float* hx, float* cx, int* mask, int* cur) {
    int i = blockIdx.x * 256 + threadIdx.x;
    if (i < BB * HH) { hx[i] = 0.f; cx[i] = 0.f; }
    if (i < BB * NP1) mask[i] = 0;
    if (i < BB) cur[i] = -1;
}

__global__ __launch_bounds__(256, 2) void k_gp(const float* __restrict__ enc,
                                               const float* __restrict__ stok,
                                               const float* __restrict__ etok,
                                               const float* __restrict__ Wih,
                                               const float* __restrict__ Whh,
                                               const int* __restrict__ cur,
                                               const float* __restrict__ hx,
                                               float* __restrict__ gp,
                                               int kch) {
    __shared__ float As[32][140];
    __shared__ float Ws[32][140];
    const int nt = blockIdx.x, ks = blockIdx.y;
    const int tid = threadIdx.x;
    const int lr = tid >> 2, lc = tid & 3;
    const int tr = tid & 15, tc = tid >> 4;
    const int kbase = ks * kch;
    const bool xpart = (kbase < HH);
    const float *arow0, *arow1;
    if (xpart) {
        int c0 = cur[lr], c1 = cur[lr + 64];
        arow0 = (c0 < 0) ? stok : (c0 == NN ? etok : enc + ((size_t)lr * NN + c0) * HH);
        arow1 = (c1 < 0) ? stok : (c1 == NN ? etok : enc + ((size_t)(lr + 64) * NN + c1) * HH);
        arow0 += kbase; arow1 += kbase;
    } else {
        arow0 = hx + (size_t)lr * HH + (kbase - HH);
        arow1 = hx + (size_t)(lr + 64) * HH + (kbase - HH);
    }
    const float* wbase = xpart ? Wih : Whh;
    const int krel = kbase & (HH - 1);
    const float* w0 = wbase + (size_t)(nt * 128 + lr) * HH + krel;
    const float* w1 = w0 + (size_t)64 * HH;
    const int ca = CPHI(lr), cb = CPHI(lr + 64);
    const int colA = tr * 8 + ((tr >> 2) << 2);
    const int colB = tc * 8 + ((tc >> 2) << 2);
    float acc[8][8] = {};
    for (int k0 = 0; k0 < kch; k0 += 32) {
        float4 va0 = *(const float4*)(arow0 + k0 + lc * 4);
        float4 va1 = *(const float4*)(arow0 + k0 + lc * 4 + 16);
        float4 va2 = *(const float4*)(arow1 + k0 + lc * 4);
        float4 va3 = *(const float4*)(arow1 + k0 + lc * 4 + 16);
        float4 vb0 = *(const float4*)(w0 + k0 + lc * 4);
        float4 vb1 = *(const float4*)(w0 + k0 + lc * 4 + 16);
        float4 vb2 = *(const float4*)(w1 + k0 + lc * 4);
        float4 vb3 = *(const float4*)(w1 + k0 + lc * 4 + 16);
        __syncthreads();
        #pragma unroll
        for (int e = 0; e < 4; e++) {
            As[lc*4+e][ca]      = ((const float*)&va0)[e];
            As[lc*4+16+e][ca]   = ((const float*)&va1)[e];
            As[lc*4+e][cb]      = ((const float*)&va2)[e];
            As[lc*4+16+e][cb]   = ((const float*)&va3)[e];
            Ws[lc*4+e][ca]      = ((const float*)&vb0)[e];
            Ws[lc*4+16+e][ca]   = ((const float*)&vb1)[e];
            Ws[lc*4+e][cb]      = ((const float*)&vb2)[e];
            Ws[lc*4+16+e][cb]   = ((const float*)&vb3)[e];
        }
        __syncthreads();
        #pragma unroll
        for (int kk = 0; kk < 32; kk++) {
            float4 A0 = *(const float4*)&As[kk][colA];
            float4 A1 = *(const float4*)&As[kk][colA + 4];
            float4 B0 = *(const float4*)&Ws[kk][colB];
            float4 B1 = *(const float4*)&Ws[kk][colB + 4];
            float av[8] = {A0.x,A0.y,A0.z,A0.w,A1.x,A1.y,A1.z,A1.w};
            float bv[8] = {B0.x,B0.y,B0.z,B0.w,B1.x,B1.y,B1.z,B1.w};
            #pragma unroll
            for (int i = 0; i < 8; i++)
                #pragma unroll
                for (int j = 0; j < 8; j++) acc[i][j] += av[i] * bv[j];
        }
        __syncthreads();
    }
    #pragma unroll
    for (int i = 0; i < 8; i++) {
        float4 o0 = make_float4(acc[i][0], acc[i][1], acc[i][2], acc[i][3]);
        float4 o1 = make_float4(acc[i][4], acc[i][5], acc[i][6], acc[i][7]);
        float* dst = gp + ((size_t)ks * 128 + tr * 8 + i) * H4 + nt * 128 + tc * 8;
        *(float4*)(dst) = o0;
        *(float4*)(dst + 4) = o1;
    }
}

__global__ __launch_bounds__(256) void k_cell(const float* __restrict__ gp,
                                              const float* __restrict__ bih,
                                              const float* __restrict__ bhh,
                                              float* __restrict__ cx,
                                              float* __restrict__ hx,
                                              int KS) {
    const int q = blockIdx.x * 256 + threadIdx.x;
    const int m = q >> 8, c0 = (q & 255) * 4;
    float4 s[4] = {};
    for (int ks = 0; ks < KS; ks++) {
        const float* base = gp + ((size_t)ks * 128 + m) * H4;
        #pragma unroll
        for (int g = 0; g < 4; g++) {
            float4 vv = *(const float4*)(base + g * HH + c0);
            s[g].x += vv.x; s[g].y += vv.y; s[g].z += vv.z; s[g].w += vv.w;
        }
    }
    float4 b1[4], b2[4];
    #pragma unroll
    for (int g = 0; g < 4; g++) {
        b1[g] = *(const float4*)(bih + g * HH + c0);
        b2[g] = *(const float4*)(bhh + g * HH + c0);
    }
    float4 cxv = *(const float4*)(cx + (size_t)m * HH + c0);
    float hn[4], cn[4];
    #pragma unroll
    for (int e = 0; e < 4; e++) {
        float gi = ((const float*)&s[0])[e] + ((const float*)&b1[0])[e] + ((const float*)&b2[0])[e];
        float gf = ((const float*)&s[1])[e] + ((const float*)&b1[1])[e] + ((const float*)&b2[1])[e];
        float gg = ((const float*)&s[2])[e] + ((const float*)&b1[2])[e] + ((const float*)&b2[2])[e];
        float go = ((const float*)&s[3])[e] + ((const float*)&b1[3])[e] + ((const float*)&b2[3])[e];
        float si = 1.f / (1.f + expf(-gi));
        float sf = 1.f / (1.f + expf(-gf));
        float so = 1.f / (1.f + expf(-go));
        float c = sf * ((const float*)&cxv)[e] + si * tanhf(gg);
        cn[e] = c;
        hn[e] = so * tanhf(c);
    }
    *(float4*)(cx + (size_t)m * HH + c0) = make_float4(cn[0], cn[1], cn[2], cn[3]);
    *(float4*)(hx + (size_t)m * HH + c0) = make_float4(hn[0], hn[1], hn[2], hn[3]);
}

__global__ __launch_bounds__(256, 2) void k_hua2(const float* __restrict__ hx,
                                                 const float* __restrict__ Ua,
                                                 float* __restrict__ hup,
                                                 int kch) {
    __shared__ float As[32][140];
    __shared__ float Us[32][72];
    const int nt = blockIdx.x, sh = blockIdx.y;
    const int tid = threadIdx.x;
    const int lr = tid >> 2, lc = tid & 3;
    const int tr = tid & 15, tc = tid >> 4;
    const int kbase = sh * kch;
    const float* a0 = hx + (size_t)lr * HH + kbase;
    const float* a1 = hx + (size_t)(lr + 64) * HH + kbase;
    const float* u0 = Ua + (size_t)(nt * 64 + lr) * HH + kbase;
    const int ca = CPHI(lr), cb = CPHI(lr + 64);
    const int colA = tr * 8 + ((tr >> 2) << 2);
    float acc[8][4] = {};
    for (int k0 = 0; k0 < kch; k0 += 32) {
        float4 va0 = *(const float4*)(a0 + k0 + lc * 4);
        float4 va1 = *(const float4*)(a0 + k0 + lc * 4 + 16);
        float4 va2 = *(const float4*)(a1 + k0 + lc * 4);
        float4 va3 = *(const float4*)(a1 + k0 + lc * 4 + 16);
        float4 vu0 = *(const float4*)(u0 + k0 + lc * 4);
        float4 vu1 = *(const float4*)(u0 + k0 + lc * 4 + 16);
        __syncthreads();
        #pragma unroll
        for (int e = 0; e < 4; e++) {
            As[lc*4+e][ca]    = ((const float*)&va0)[e];
            As[lc*4+16+e][ca] = ((const float*)&va1)[e];
            As[lc*4+e][cb]    = ((const float*)&va2)[e];
            As[lc*4+16+e][cb] = ((const float*)&va3)[e];
            Us[lc*4+e][lr]    = ((const float*)&vu0)[e];
            Us[lc*4+16+e][lr] = ((const float*)&vu1)[e];
        }
        __syncthreads();
        #pragma unroll
        for (int kk = 0; kk < 32; kk++) {
            float4 A0 = *(const float4*)&As[kk][colA];
            float4 A1 = *(const float4*)&As[kk][colA + 4];
            float4 U0 = *(const float4*)&Us[kk][tc * 4];
            float av[8] = {A0.x,A0.y,A0.z,A0.w,A1.x,A1.y,A1.z,A1.w};
            float uv[4] = {U0.x,U0.y,U0.z,U0.w};
            #pragma unroll
            for (int i = 0; i < 8; i++)
                #pragma unroll
                for (int j = 0; j < 4; j++) acc[i][j] += av[i] * uv[j];
        }
        __syncthreads();
    }
    #pragma unroll
    for (int i = 0; i < 8; i++) {
        float4 o = make_float4(acc[i][0], acc[i][1], acc[i][2], acc[i][3]);
        *(float4*)(hup + ((size_t)sh * 128 + tr * 8 + i) * HH + nt * 64 + tc * 4) = o;
    }
}

__global__ __launch_bounds__(256) void k_sc(const float* __restrict__ encWa,
                                            const float* __restrict__ hup,
                                            const float* __restrict__ vvec,
                                            float* __restrict__ scores,
                                            int SH) {
    const int b = blockIdx.x >> 2, q = blockIdx.x & 3;
    const int t = threadIdx.x;
    __shared__ float hu[HH];
    __shared__ float vv[HH];
    {
        float4 s = {};
        for (int sh = 0; sh < SH; sh++) {
            float4 p = *(const float4*)(hup + ((size_t)sh * 128 + b) * HH + t * 4);
            s.x += p.x; s.y += p.y; s.z += p.z; s.w += p.w;
        }
        *(float4*)(&hu[t * 4]) = s;
        *(float4*)(&vv[t * 4]) = *(const float4*)(vvec + t * 4);
    }
    __syncthreads();
    const int wave = t >> 6, lane = t & 63;
    const int limit = (q == 3) ? NP1 : (q + 1) * 64;
    int n = q * 64 + wave;
    if (n < limit) {
        const float4 hh4 = *(const float4*)(&hu[lane * 4]);
        const float4 vv4 = *(const float4*)(&vv[lane * 4]);
        float4 e = *(const float4*)(encWa + ((size_t)b * NP1 + n) * HH + lane * 4);
        while (n < limit) {
            int n2 = n + 4;
            float4 e2 = e;
            if (n2 < limit)
                e2 = *(const float4*)(encWa + ((size_t)b * NP1 + n2) * HH + lane * 4);
            float s = vv4.x * tanhf(e.x + hh4.x) + vv4.y * tanhf(e.y + hh4.y)
                    + vv4.z * tanhf(e.z + hh4.z) + vv4.w * tanhf(e.w + hh4.w);
            #pragma unroll
            for (int off = 32; off; off >>= 1) s += __shfl_down(s, off);
            if (lane == 0) scores[b * NP1 + n] = s;
            e = e2; n = n2;
        }
    }
}

__global__ __launch_bounds__(256) void k_fin(const float* __restrict__ scores,
                                             int* __restrict__ mask,
                                             int* __restrict__ cur,
                                             float* __restrict__ out_lp,
                                             float* __restrict__ out_idx,
                                             int step) {
    const int b = blockIdx.x;
    const int t = threadIdx.x;
    __shared__ float rv[256];
    __shared__ int   ri[256];
    const bool m_t = mask[b * NP1 + t] != 0;
    const float va = m_t ? -INFINITY : scores[b * NP1 + t];
    float va256 = 0.f;
    if (t == 0) va256 = (mask[b * NP1 + NN] != 0) ? -INFINITY : scores[b * NP1 + NN];
    float myv = va; int myi = t;
    if (t == 0) { if (va256 > myv) { myv = va256; myi = NN; } }
    rv[t] = myv; ri[t] = myi;
    __syncthreads();
    for (int s = 128; s; s >>= 1) {
        if (t < s) {
            float ov = rv[t + s]; int oi = ri[t + s];
            if (ov > rv[t] || (ov == rv[t] && oi < ri[t])) { rv[t] = ov; ri[t] = oi; }
        }
        __syncthreads();
    }
    const float vmax = rv[0]; const int amax = ri[0];
    __syncthreads();
    float es = expf(va - vmax);
    if (t == 0) es += expf(va256 - vmax);
    rv[t] = es;
    __syncthreads();
    for (int s = 128; s; s >>= 1) {
        if (t < s) rv[t] += rv[t + s];
        __syncthreads();
    }
    const float lse = vmax + logf(rv[0]);
    out_lp[((size_t)b * NP1 + step) * NP1 + t] = fmaxf(va - lse, -1e30f);
    if (t == 0) {
        out_lp[((size_t)b * NP1 + step) * NP1 + NN] = fmaxf(va256 - lse, -1e30f);
        out_idx[(size_t)b * NP1 + step] = (float)amax;
        cur[b] = amax;
        if (amax < NN) mask[b * NP1 + amax] = 1;
    }
}

// ---------------------------------------------------------------------------
extern "C" void kernel_launch(void* const* d_in, const int* in_sizes, int n_in,
                              void* d_out, int out_size, void* d_ws, size_t ws_size,
                              hipStream_t stream) {
    const float* enc  = (const float*)d_in[0];
    const float* Wih  = (const float*)d_in[1];
    const float* Whh  = (const float*)d_in[2];
    const float* bih  = (const float*)d_in[3];
    const float* bhh  = (const float*)d_in[4];
    const float* Wa   = (const float*)d_in[5];
    const float* Ua   = (const float*)d_in[6];
    const float* v    = (const float*)d_in[7];
    const float* stok = (const float*)d_in[8];
    const float* etok = (const float*)d_in[9];
    float* out = (float*)d_out;
    float* out_idx = out + (size_t)BB * NP1 * NP1;

    const size_t ENCWA_F = (size_t)BB * NP1 * HH;
    const size_t INT_TAIL = ((size_t)BB * NP1 + BB) * 4;

    auto need = [&](int KS, int SH) -> size_t {
        return (ENCWA_F + (size_t)KS * BB * H4 + (size_t)SH * BB * HH
                + 2 * (size_t)BB * HH + (size_t)BB * NP1) * 4 + INT_TAIL;
    };

    if (ws_size >= need(16, 16)) {
        float* ws = (float*)d_ws;
        float* encWa = ws;                       size_t off = ENCWA_F;
        float* gp    = ws + off;  off += (size_t)16 * BB * H4;
        float* hup   = ws + off;  off += (size_t)16 * BB * HH;
        float* hx    = ws + off;  off += (size_t)BB * HH;
        float* cx    = ws + off;  off += (size_t)BB * HH;
        float* scores= ws + off;  off += (size_t)BB * NP1;
        int* mask = (int*)(ws + off);
        int* cur  = mask + BB * NP1;

        k_encWa2<<<dim3(257, 8), 256, 0, stream>>>(enc, etok, Wa, encWa);
        void* args[] = { (void*)&enc, (void*)&stok, (void*)&etok, (void*)&Wih,
                         (void*)&Whh, (void*)&bih, (void*)&bhh, (void*)&Ua,
                         (void*)&v, (void*)&encWa, (void*)&gp, (void*)&hup,
                         (void*)&hx, (void*)&cx, (void*)&scores, (void*)&mask,
                         (void*)&cur, (void*)&out, (void*)&out_idx };
        hipLaunchCooperativeKernel((const void*)k_decode, dim3(512), dim3(256),
                                   args, 0, stream);
        return;
    }

    // ---------------- fallback: round-3 separate-kernel loop ---------------
    int KS = 0, SH = 0;
    if (ws_size >= need(8, 8))      { KS = 8; SH = 8; }
    else if (ws_size >= need(2, 2)) { KS = 2; SH = 2; }
    if (KS == 0) return;

    float* ws = (float*)d_ws;
    float* encWa = ws;                       size_t off = ENCWA_F;
    float* gp    = ws + off;  off += (size_t)KS * BB * H4;
    float* hup   = ws + off;  off += (size_t)SH * BB * HH;
    float* hx    = ws + off;  off += (size_t)BB * HH;
    float* cx    = ws + off;  off += (size_t)BB * HH;
    float* scores= ws + off;  off += (size_t)BB * NP1;
    int* mask = (int*)(ws + off);
    int* cur  = mask + BB * NP1;
    const int kch  = 2 * HH / KS;
    const int kch2 = HH / SH;

    k_init<<<512, 256, 0, stream>>>(hx, cx, mask, cur);
    k_encWa2<<<dim3(257, 8), 256, 0, stream>>>(enc, etok, Wa, encWa);
    for (int t = 0; t < NP1; t++) {
        k_gp<<<dim3(32, KS), 256, 0, stream>>>(enc, stok, etok, Wih, Whh,
                                               cur, hx, gp, kch);
        k_cell<<<128, 256, 0, stream>>>(gp, bih, bhh, cx, hx, KS);
        k_hua2<<<dim3(16, SH), 256, 0, stream>>>(hx, Ua, hup, kch2);
        k_sc<<<512, 256, 0, stream>>>(encWa, hup, v, scores, SH);
        k_fin<<<128, 256, 0, stream>>>(scores, mask, cur, out, out_idx, t);
    }
}